// Round 6
// baseline (1876.558 us; speedup 1.0000x reference)
//
#include <hip/hip_runtime.h>

// CapsuleNet forward, fully fused, fp32 — wave-per-output-capsule decomposition.
//
// Block: 640 threads = 10 waves, wave o owns output capsule o, for M=8 batches.
// Lane layout: lane = ig*16 + d,  ig in [0,4), d in [0,16).
//   Lane (ig,d) owns priors P[m][k] for i = 4k+ig (k=0..8), output dim d.
//
// Hard-won lessons encoded here:
//  R1/R3: loops indexing register arrays MUST be source-level (macro) unrolled.
//    "#pragma unroll" silently fails with convergent intrinsics (DPP) in the
//    body -> runtime indexing -> scratch spill (935 MB). Macros only.
//  R2: __shfl_xor is DS-pipe; intra-16-lane reductions use DPP (VALU pipe).
//  R4/R5: DS pipe wave-instrs cut via half-exchange caps reads (row_ror:8),
//    k-contiguous padded pl rows (b128), exp moved out of wave-wide phases.
//  R6: M=4 -> 8 amortizes per-block fixed costs (6 barriers, conv phase, the
//    FULL 184KB lin_w read per block) over 2x batches; dl buffer eliminated —
//    AG2 rewrites pl in probability domain (p1 * exp(delta2)) reusing the
//    p1 values already in registers from IT1 (3 pure b128/b32 writes, 0 reads);
//    norm2 becomes a plain exp-free renormalize.

constexpr int OC = 10, NI = 36, OD = 16, IL = 8;
constexpr int M  = 8;              // batches per block
constexpr int NT = 64 * OC;        // 640 threads
constexpr int PROW = 12;           // padded k-row stride (floats): 16B-aligned b128

template<int CTRL>
__device__ __forceinline__ float dpp_movf(float v) {
    return __int_as_float(__builtin_amdgcn_update_dpp(
        0, __float_as_int(v), CTRL, 0xF, 0xF, true));
}
// Full sum over each 16-lane row, result in every lane. Pure VALU (no DS pipe).
__device__ __forceinline__ float rowsum16(float v) {
    v += dpp_movf<0xB1>(v);    // quad_perm [1,0,3,2] : pair sums
    v += dpp_movf<0x4E>(v);    // quad_perm [2,3,0,1] : quad sums
    v += dpp_movf<0x141>(v);   // row_half_mirror     : 8-group sums
    v += dpp_movf<0x140>(v);   // row_mirror          : 16-row sum
    return v;
}

__global__ __launch_bounds__(NT, 5)
void capsnet_kernel(const float* __restrict__ xg,
                    const float* __restrict__ cwg,
                    const float* __restrict__ lwg,
                    float* __restrict__ outg)
{
    __shared__ float xs[M * 9];
    __shared__ float cw[288];
    __shared__ float caps[M * NI * IL];        // [m][i][l]
    __shared__ float pl[M * OC * 4 * PROW];    // [m][o][ig][12]: deltas -> probs

    const int t  = threadIdx.x;
    const int b0 = blockIdx.x * M;

    if (t < M * 9) xs[t] = xg[b0 * 9 + t];
    if (t < 288)   cw[t] = cwg[t];
    __syncthreads();

    // ---- conv (1->32ch, 3x3, pad 1) + squash over capsule length -> caps ----
    if (t < M * NI) {   // 288 threads
        const int m  = t / NI;
        const int ci = t % NI;
        const int cg = ci & 3;
        const int wx = (ci >> 2) % 3;
        const int hx = ci / 12;
        float acc[IL] = {};
        #pragma unroll
        for (int kh = 0; kh < 3; ++kh) {
            const int xh = hx + kh - 1;
            if (xh < 0 || xh > 2) continue;
            #pragma unroll
            for (int kw = 0; kw < 3; ++kw) {
                const int xw = wx + kw - 1;
                if (xw < 0 || xw > 2) continue;
                const float xv = xs[m * 9 + xh * 3 + xw];
                #pragma unroll
                for (int l = 0; l < IL; ++l)
                    acc[l] += xv * cw[(cg * 8 + l) * 9 + kh * 3 + kw];
            }
        }
        float n2 = 0.f;
        #pragma unroll
        for (int l = 0; l < IL; ++l) n2 += acc[l] * acc[l];
        const float sc = n2 / (1.f + n2) * rsqrtf(n2 + 1e-8f);
        #pragma unroll
        for (int l = 0; l < IL; ++l) caps[t * IL + l] = acc[l] * sc;
    }
    __syncthreads();

    const int o    = t >> 6;      // wave id == output capsule
    const int lane = t & 63;
    const int ig   = lane >> 4;   // i-subgroup: i = 4k + ig
    const int d    = lane & 15;   // output dim
    const int q    = d >> 3;      // caps half this lane loads (partner = d^8)

    // ---- priors: P[m][k] = sum_l w[o][4k+ig][d][l] * caps[m][4k+ig][l] ----
    // Lane loads caps half q (1 x b128); partner half via row_ror:8 DPP.
    // Own-half-first w addressing avoids per-lane selects. Literal indices only.
    float P[M][9];
    const float* wp = lwg + ((o * NI + ig) * OD + d) * IL;
    const int qo = q * 4, qx = (q ^ 1) * 4;

#define PRI_M(k_, m_) { \
    const float4 co = *reinterpret_cast<const float4*>( \
        &caps[((m_) * NI + 4*(k_) + ig) * IL + qo]); \
    float4 cx; \
    cx.x = dpp_movf<0x128>(co.x); \
    cx.y = dpp_movf<0x128>(co.y); \
    cx.z = dpp_movf<0x128>(co.z); \
    cx.w = dpp_movf<0x128>(co.w); \
    P[m_][k_] = wq.x * co.x + wq.y * co.y + wq.z * co.z + wq.w * co.w \
              + wr.x * cx.x + wr.y * cx.y + wr.z * cx.z + wr.w * cx.w; }
#define PRI_K(k_) { \
    const float4 wq = *reinterpret_cast<const float4*>(wp + (k_) * (4 * OD * IL) + qo); \
    const float4 wr = *reinterpret_cast<const float4*>(wp + (k_) * (4 * OD * IL) + qx); \
    PRI_M(k_, 0) PRI_M(k_, 1) PRI_M(k_, 2) PRI_M(k_, 3) \
    PRI_M(k_, 4) PRI_M(k_, 5) PRI_M(k_, 6) PRI_M(k_, 7) }
    PRI_K(0) PRI_K(1) PRI_K(2) PRI_K(3) PRI_K(4) PRI_K(5) PRI_K(6) PRI_K(7) PRI_K(8)
#undef PRI_K
#undef PRI_M

    // ---- iteration 0 (uniform p=0.1) + agreement-1: pl = raw delta1 ----
    // ov is a per-m scalar consumed immediately (no ov[] array -> fewer regs).
#define RT0_M(m_) { \
    float s = P[m_][0] + P[m_][1] + P[m_][2] + P[m_][3] + P[m_][4] \
            + P[m_][5] + P[m_][6] + P[m_][7] + P[m_][8]; \
    s *= 0.1f; \
    s += __shfl_xor(s, 16); \
    s += __shfl_xor(s, 32); \
    const float n2 = rowsum16(s * s); \
    const float sc = n2 / (1.f + n2) * rsqrtf(n2 + 1e-8f); \
    const float ovm = s * sc; \
    const float a0 = rowsum16(P[m_][0] * ovm); \
    const float a1 = rowsum16(P[m_][1] * ovm); \
    const float a2 = rowsum16(P[m_][2] * ovm); \
    const float a3 = rowsum16(P[m_][3] * ovm); \
    const float a4 = rowsum16(P[m_][4] * ovm); \
    const float a5 = rowsum16(P[m_][5] * ovm); \
    const float a6 = rowsum16(P[m_][6] * ovm); \
    const float a7 = rowsum16(P[m_][7] * ovm); \
    const float a8 = rowsum16(P[m_][8] * ovm); \
    if (d == 0) { \
        float* wb = &pl[(((m_) * OC + o) * 4 + ig) * PROW]; \
        *reinterpret_cast<float4*>(wb)     = make_float4(a0, a1, a2, a3); \
        *reinterpret_cast<float4*>(wb + 4) = make_float4(a4, a5, a6, a7); \
        wb[8] = a8; \
    } }
    RT0_M(0) RT0_M(1) RT0_M(2) RT0_M(3) RT0_M(4) RT0_M(5) RT0_M(6) RT0_M(7)
#undef RT0_M
    __syncthreads();

    // norm1: pl <- softmax_o(exp(raw delta))   (288 threads; literal indices)
    if (t < M * NI) {
        const int m = t / NI, r = t % NI;
        float* base = &pl[(m * OC * 4 + (r / 9)) * PROW + (r % 9)];
        float v[OC];
        float ss = 0.f;
#define LD1(oo) { v[oo] = __expf(base[(oo) * 4 * PROW]); ss += v[oo]; }
        LD1(0) LD1(1) LD1(2) LD1(3) LD1(4) LD1(5) LD1(6) LD1(7) LD1(8) LD1(9)
#undef LD1
        const float inv = 1.f / ss;
#define ST1(oo) base[(oo) * 4 * PROW] = v[oo] * inv;
        ST1(0) ST1(1) ST1(2) ST1(3) ST1(4) ST1(5) ST1(6) ST1(7) ST1(8) ST1(9)
#undef ST1
    }
    __syncthreads();

    // ---- iteration 1 + agreement-2 ----
    // AG2 updates pl in probability domain: pl <- p1 * exp(delta2). The p1
    // row (pA/pB/p8) is already in registers from the IT1 read -> 3 pure
    // writes, no RMW read. The missing 1/D renorm is uniform over o per
    // (m,i) and cancels in norm2's renormalize.
#define RT1_M(m_) { \
    const float* pb = &pl[(((m_) * OC + o) * 4 + ig) * PROW]; \
    const float4 pA = *reinterpret_cast<const float4*>(pb); \
    const float4 pB = *reinterpret_cast<const float4*>(pb + 4); \
    const float p8  = pb[8]; \
    float s = pA.x * P[m_][0] + pA.y * P[m_][1] + pA.z * P[m_][2] + pA.w * P[m_][3] \
            + pB.x * P[m_][4] + pB.y * P[m_][5] + pB.z * P[m_][6] + pB.w * P[m_][7] \
            + p8   * P[m_][8]; \
    s += __shfl_xor(s, 16); \
    s += __shfl_xor(s, 32); \
    const float n2 = rowsum16(s * s); \
    const float sc = n2 / (1.f + n2) * rsqrtf(n2 + 1e-8f); \
    const float ovm = s * sc; \
    const float e0 = __expf(rowsum16(P[m_][0] * ovm)); \
    const float e1 = __expf(rowsum16(P[m_][1] * ovm)); \
    const float e2 = __expf(rowsum16(P[m_][2] * ovm)); \
    const float e3 = __expf(rowsum16(P[m_][3] * ovm)); \
    const float e4 = __expf(rowsum16(P[m_][4] * ovm)); \
    const float e5 = __expf(rowsum16(P[m_][5] * ovm)); \
    const float e6 = __expf(rowsum16(P[m_][6] * ovm)); \
    const float e7 = __expf(rowsum16(P[m_][7] * ovm)); \
    const float e8 = __expf(rowsum16(P[m_][8] * ovm)); \
    if (d == 0) { \
        float* wb = &pl[(((m_) * OC + o) * 4 + ig) * PROW]; \
        *reinterpret_cast<float4*>(wb) = \
            make_float4(pA.x * e0, pA.y * e1, pA.z * e2, pA.w * e3); \
        *reinterpret_cast<float4*>(wb + 4) = \
            make_float4(pB.x * e4, pB.y * e5, pB.z * e6, pB.w * e7); \
        wb[8] = p8 * e8; \
    } }
    RT1_M(0) RT1_M(1) RT1_M(2) RT1_M(3) RT1_M(4) RT1_M(5) RT1_M(6) RT1_M(7)
#undef RT1_M
    __syncthreads();

    // norm2: plain renormalize over o (no exp)
    if (t < M * NI) {
        const int m = t / NI, r = t % NI;
        float* base = &pl[(m * OC * 4 + (r / 9)) * PROW + (r % 9)];
        float v[OC];
        float ss = 0.f;
#define LD2(oo) { v[oo] = base[(oo) * 4 * PROW]; ss += v[oo]; }
        LD2(0) LD2(1) LD2(2) LD2(3) LD2(4) LD2(5) LD2(6) LD2(7) LD2(8) LD2(9)
#undef LD2
        const float inv = 1.f / ss;
#define ST2(oo) base[(oo) * 4 * PROW] = v[oo] * inv;
        ST2(0) ST2(1) ST2(2) ST2(3) ST2(4) ST2(5) ST2(6) ST2(7) ST2(8) ST2(9)
#undef ST2
    }
    __syncthreads();

    // ---- routing iteration 2 (final): emit out ----
#define RT2_M(m_) { \
    const float* pb = &pl[(((m_) * OC + o) * 4 + ig) * PROW]; \
    const float4 pA = *reinterpret_cast<const float4*>(pb); \
    const float4 pB = *reinterpret_cast<const float4*>(pb + 4); \
    const float p8  = pb[8]; \
    float s = pA.x * P[m_][0] + pA.y * P[m_][1] + pA.z * P[m_][2] + pA.w * P[m_][3] \
            + pB.x * P[m_][4] + pB.y * P[m_][5] + pB.z * P[m_][6] + pB.w * P[m_][7] \
            + p8   * P[m_][8]; \
    s += __shfl_xor(s, 16); \
    s += __shfl_xor(s, 32); \
    const float n2 = rowsum16(s * s); \
    const float sc = n2 / (1.f + n2) * rsqrtf(n2 + 1e-8f); \
    if (ig == 0) outg[(b0 + (m_)) * (OC * OD) + o * OD + d] = s * sc; }
    RT2_M(0) RT2_M(1) RT2_M(2) RT2_M(3) RT2_M(4) RT2_M(5) RT2_M(6) RT2_M(7)
#undef RT2_M
}

extern "C" void kernel_launch(void* const* d_in, const int* in_sizes, int n_in,
                              void* d_out, int out_size, void* d_ws, size_t ws_size,
                              hipStream_t stream) {
    const float* x  = (const float*)d_in[0];   // [B,1,3,3]
    const float* cwp = (const float*)d_in[1];  // [32,1,3,3]
    const float* lw = (const float*)d_in[2];   // [10,36,16,8]
    float* out = (float*)d_out;                // [B,10,16]
    const int B = in_sizes[0] / 9;             // 16384
    dim3 grid(B / M), block(NT);
    capsnet_kernel<<<grid, block, 0, stream>>>(x, cwp, lw, out);
}

// Round 7
// 1595.085 us; speedup vs baseline: 1.1765x; 1.1765x over previous
//
#include <hip/hip_runtime.h>

// CapsuleNet forward, fully fused, fp32 — wave-per-output-capsule decomposition.
//
// Block: 640 threads = 10 waves, wave o owns output capsule o, for M=8 batches.
// Lane layout: lane = ig*16 + d,  ig in [0,4), d in [0,16).
//   Lane (ig,d) owns priors P[m][k] for i = 4k+ig (k=0..8), output dim d.
//
// Hard-won lessons encoded here:
//  R1/R3/R6: the REAL spill trigger is the __launch_bounds__ VGPR cap
//    (512/min_waves: 5 -> ~102, 6 -> ~85). When the kernel's true need
//    exceeds the cap, the compiler demotes whole register arrays to scratch
//    (signature: VGPR_Count ~48 + GBs of FETCH/WRITE). M=8 needs ~95 VGPRs
//    -> bound must be 4 (cap 128). Occupancy still lands at 2 blocks/CU if
//    actual VGPR <= 102. Macro-unrolled literal indices remain mandatory.
//  R2: __shfl_xor is DS-pipe; intra-16-lane reductions use DPP (VALU pipe).
//  R4/R5: DS pipe wave-instrs cut via half-exchange caps reads (row_ror:8),
//    k-contiguous padded pl rows (b128), exp kept out of 10-wave phases
//    where possible; dl buffer eliminated (probability-domain AG2).
//  R6->R7: AG stores interleaved with the rowsum computes (a0-a3, store,
//    a4-a7, store, a8) to cap live scalars at 4 instead of 9.

constexpr int OC = 10, NI = 36, OD = 16, IL = 8;
constexpr int M  = 8;              // batches per block
constexpr int NT = 64 * OC;        // 640 threads
constexpr int PROW = 12;           // padded k-row stride (floats): 16B-aligned b128

template<int CTRL>
__device__ __forceinline__ float dpp_movf(float v) {
    return __int_as_float(__builtin_amdgcn_update_dpp(
        0, __float_as_int(v), CTRL, 0xF, 0xF, true));
}
// Full sum over each 16-lane row, result in every lane. Pure VALU (no DS pipe).
__device__ __forceinline__ float rowsum16(float v) {
    v += dpp_movf<0xB1>(v);    // quad_perm [1,0,3,2] : pair sums
    v += dpp_movf<0x4E>(v);    // quad_perm [2,3,0,1] : quad sums
    v += dpp_movf<0x141>(v);   // row_half_mirror     : 8-group sums
    v += dpp_movf<0x140>(v);   // row_mirror          : 16-row sum
    return v;
}

__global__ __launch_bounds__(NT, 4)
void capsnet_kernel(const float* __restrict__ xg,
                    const float* __restrict__ cwg,
                    const float* __restrict__ lwg,
                    float* __restrict__ outg)
{
    __shared__ float xs[M * 9];
    __shared__ float cw[288];
    __shared__ float caps[M * NI * IL];        // [m][i][l]
    __shared__ float pl[M * OC * 4 * PROW];    // [m][o][ig][12]: deltas -> probs

    const int t  = threadIdx.x;
    const int b0 = blockIdx.x * M;

    if (t < M * 9) xs[t] = xg[b0 * 9 + t];
    if (t < 288)   cw[t] = cwg[t];
    __syncthreads();

    // ---- conv (1->32ch, 3x3, pad 1) + squash over capsule length -> caps ----
    if (t < M * NI) {   // 288 threads
        const int m  = t / NI;
        const int ci = t % NI;
        const int cg = ci & 3;
        const int wx = (ci >> 2) % 3;
        const int hx = ci / 12;
        float acc[IL] = {};
        #pragma unroll
        for (int kh = 0; kh < 3; ++kh) {
            const int xh = hx + kh - 1;
            if (xh < 0 || xh > 2) continue;
            #pragma unroll
            for (int kw = 0; kw < 3; ++kw) {
                const int xw = wx + kw - 1;
                if (xw < 0 || xw > 2) continue;
                const float xv = xs[m * 9 + xh * 3 + xw];
                #pragma unroll
                for (int l = 0; l < IL; ++l)
                    acc[l] += xv * cw[(cg * 8 + l) * 9 + kh * 3 + kw];
            }
        }
        float n2 = 0.f;
        #pragma unroll
        for (int l = 0; l < IL; ++l) n2 += acc[l] * acc[l];
        const float sc = n2 / (1.f + n2) * rsqrtf(n2 + 1e-8f);
        #pragma unroll
        for (int l = 0; l < IL; ++l) caps[t * IL + l] = acc[l] * sc;
    }
    __syncthreads();

    const int o    = t >> 6;      // wave id == output capsule
    const int lane = t & 63;
    const int ig   = lane >> 4;   // i-subgroup: i = 4k + ig
    const int d    = lane & 15;   // output dim
    const int q    = d >> 3;      // caps half this lane loads (partner = d^8)

    // ---- priors: P[m][k] = sum_l w[o][4k+ig][d][l] * caps[m][4k+ig][l] ----
    // Lane loads caps half q (1 x b128); partner half via row_ror:8 DPP.
    // Own-half-first w addressing avoids per-lane selects. Literal indices only.
    float P[M][9];
    const float* wp = lwg + ((o * NI + ig) * OD + d) * IL;
    const int qo = q * 4, qx = (q ^ 1) * 4;

#define PRI_M(k_, m_) { \
    const float4 co = *reinterpret_cast<const float4*>( \
        &caps[((m_) * NI + 4*(k_) + ig) * IL + qo]); \
    float4 cx; \
    cx.x = dpp_movf<0x128>(co.x); \
    cx.y = dpp_movf<0x128>(co.y); \
    cx.z = dpp_movf<0x128>(co.z); \
    cx.w = dpp_movf<0x128>(co.w); \
    P[m_][k_] = wq.x * co.x + wq.y * co.y + wq.z * co.z + wq.w * co.w \
              + wr.x * cx.x + wr.y * cx.y + wr.z * cx.z + wr.w * cx.w; }
#define PRI_K(k_) { \
    const float4 wq = *reinterpret_cast<const float4*>(wp + (k_) * (4 * OD * IL) + qo); \
    const float4 wr = *reinterpret_cast<const float4*>(wp + (k_) * (4 * OD * IL) + qx); \
    PRI_M(k_, 0) PRI_M(k_, 1) PRI_M(k_, 2) PRI_M(k_, 3) \
    PRI_M(k_, 4) PRI_M(k_, 5) PRI_M(k_, 6) PRI_M(k_, 7) }
    PRI_K(0) PRI_K(1) PRI_K(2) PRI_K(3) PRI_K(4) PRI_K(5) PRI_K(6) PRI_K(7) PRI_K(8)
#undef PRI_K
#undef PRI_M

    // ---- iteration 0 (uniform p=0.1) + agreement-1: pl = raw delta1 ----
    // Stores interleaved with computes: at most 4 reduction results live.
#define RT0_M(m_) { \
    float s = P[m_][0] + P[m_][1] + P[m_][2] + P[m_][3] + P[m_][4] \
            + P[m_][5] + P[m_][6] + P[m_][7] + P[m_][8]; \
    s *= 0.1f; \
    s += __shfl_xor(s, 16); \
    s += __shfl_xor(s, 32); \
    const float n2 = rowsum16(s * s); \
    const float sc = n2 / (1.f + n2) * rsqrtf(n2 + 1e-8f); \
    const float ovm = s * sc; \
    float* wb = &pl[(((m_) * OC + o) * 4 + ig) * PROW]; \
    { \
        const float a0 = rowsum16(P[m_][0] * ovm); \
        const float a1 = rowsum16(P[m_][1] * ovm); \
        const float a2 = rowsum16(P[m_][2] * ovm); \
        const float a3 = rowsum16(P[m_][3] * ovm); \
        if (d == 0) *reinterpret_cast<float4*>(wb) = make_float4(a0, a1, a2, a3); \
    } \
    { \
        const float a4 = rowsum16(P[m_][4] * ovm); \
        const float a5 = rowsum16(P[m_][5] * ovm); \
        const float a6 = rowsum16(P[m_][6] * ovm); \
        const float a7 = rowsum16(P[m_][7] * ovm); \
        if (d == 0) *reinterpret_cast<float4*>(wb + 4) = make_float4(a4, a5, a6, a7); \
    } \
    { \
        const float a8 = rowsum16(P[m_][8] * ovm); \
        if (d == 0) wb[8] = a8; \
    } }
    RT0_M(0) RT0_M(1) RT0_M(2) RT0_M(3) RT0_M(4) RT0_M(5) RT0_M(6) RT0_M(7)
#undef RT0_M
    __syncthreads();

    // norm1: pl <- softmax_o(exp(raw delta))   (288 threads; literal indices)
    if (t < M * NI) {
        const int m = t / NI, r = t % NI;
        float* base = &pl[(m * OC * 4 + (r / 9)) * PROW + (r % 9)];
        float v[OC];
        float ss = 0.f;
#define LD1(oo) { v[oo] = __expf(base[(oo) * 4 * PROW]); ss += v[oo]; }
        LD1(0) LD1(1) LD1(2) LD1(3) LD1(4) LD1(5) LD1(6) LD1(7) LD1(8) LD1(9)
#undef LD1
        const float inv = 1.f / ss;
#define ST1(oo) base[(oo) * 4 * PROW] = v[oo] * inv;
        ST1(0) ST1(1) ST1(2) ST1(3) ST1(4) ST1(5) ST1(6) ST1(7) ST1(8) ST1(9)
#undef ST1
    }
    __syncthreads();

    // ---- iteration 1 + agreement-2 ----
    // AG2 updates pl in probability domain: pl <- p1 * exp(delta2). The p1
    // row (pA/pB/p8) is already in registers from the IT1 read -> 3 pure
    // writes, no RMW read. The missing uniform-over-o renorm factor cancels
    // in norm2's renormalize. Stores interleaved to cap live temporaries.
#define RT1_M(m_) { \
    float* wb = &pl[(((m_) * OC + o) * 4 + ig) * PROW]; \
    const float4 pA = *reinterpret_cast<const float4*>(wb); \
    const float4 pB = *reinterpret_cast<const float4*>(wb + 4); \
    const float p8  = wb[8]; \
    float s = pA.x * P[m_][0] + pA.y * P[m_][1] + pA.z * P[m_][2] + pA.w * P[m_][3] \
            + pB.x * P[m_][4] + pB.y * P[m_][5] + pB.z * P[m_][6] + pB.w * P[m_][7] \
            + p8   * P[m_][8]; \
    s += __shfl_xor(s, 16); \
    s += __shfl_xor(s, 32); \
    const float n2 = rowsum16(s * s); \
    const float sc = n2 / (1.f + n2) * rsqrtf(n2 + 1e-8f); \
    const float ovm = s * sc; \
    { \
        const float e0 = __expf(rowsum16(P[m_][0] * ovm)); \
        const float e1 = __expf(rowsum16(P[m_][1] * ovm)); \
        const float e2 = __expf(rowsum16(P[m_][2] * ovm)); \
        const float e3 = __expf(rowsum16(P[m_][3] * ovm)); \
        if (d == 0) *reinterpret_cast<float4*>(wb) = \
            make_float4(pA.x * e0, pA.y * e1, pA.z * e2, pA.w * e3); \
    } \
    { \
        const float e4 = __expf(rowsum16(P[m_][4] * ovm)); \
        const float e5 = __expf(rowsum16(P[m_][5] * ovm)); \
        const float e6 = __expf(rowsum16(P[m_][6] * ovm)); \
        const float e7 = __expf(rowsum16(P[m_][7] * ovm)); \
        if (d == 0) *reinterpret_cast<float4*>(wb + 4) = \
            make_float4(pB.x * e4, pB.y * e5, pB.z * e6, pB.w * e7); \
    } \
    { \
        const float e8 = __expf(rowsum16(P[m_][8] * ovm)); \
        if (d == 0) wb[8] = p8 * e8; \
    } }
    RT1_M(0) RT1_M(1) RT1_M(2) RT1_M(3) RT1_M(4) RT1_M(5) RT1_M(6) RT1_M(7)
#undef RT1_M
    __syncthreads();

    // norm2: plain renormalize over o (no exp)
    if (t < M * NI) {
        const int m = t / NI, r = t % NI;
        float* base = &pl[(m * OC * 4 + (r / 9)) * PROW + (r % 9)];
        float v[OC];
        float ss = 0.f;
#define LD2(oo) { v[oo] = base[(oo) * 4 * PROW]; ss += v[oo]; }
        LD2(0) LD2(1) LD2(2) LD2(3) LD2(4) LD2(5) LD2(6) LD2(7) LD2(8) LD2(9)
#undef LD2
        const float inv = 1.f / ss;
#define ST2(oo) base[(oo) * 4 * PROW] = v[oo] * inv;
        ST2(0) ST2(1) ST2(2) ST2(3) ST2(4) ST2(5) ST2(6) ST2(7) ST2(8) ST2(9)
#undef ST2
    }
    __syncthreads();

    // ---- routing iteration 2 (final): emit out ----
#define RT2_M(m_) { \
    const float* pb = &pl[(((m_) * OC + o) * 4 + ig) * PROW]; \
    const float4 pA = *reinterpret_cast<const float4*>(pb); \
    const float4 pB = *reinterpret_cast<const float4*>(pb + 4); \
    const float p8  = pb[8]; \
    float s = pA.x * P[m_][0] + pA.y * P[m_][1] + pA.z * P[m_][2] + pA.w * P[m_][3] \
            + pB.x * P[m_][4] + pB.y * P[m_][5] + pB.z * P[m_][6] + pB.w * P[m_][7] \
            + p8   * P[m_][8]; \
    s += __shfl_xor(s, 16); \
    s += __shfl_xor(s, 32); \
    const float n2 = rowsum16(s * s); \
    const float sc = n2 / (1.f + n2) * rsqrtf(n2 + 1e-8f); \
    if (ig == 0) outg[(b0 + (m_)) * (OC * OD) + o * OD + d] = s * sc; }
    RT2_M(0) RT2_M(1) RT2_M(2) RT2_M(3) RT2_M(4) RT2_M(5) RT2_M(6) RT2_M(7)
#undef RT2_M
}

extern "C" void kernel_launch(void* const* d_in, const int* in_sizes, int n_in,
                              void* d_out, int out_size, void* d_ws, size_t ws_size,
                              hipStream_t stream) {
    const float* x  = (const float*)d_in[0];   // [B,1,3,3]
    const float* cwp = (const float*)d_in[1];  // [32,1,3,3]
    const float* lw = (const float*)d_in[2];   // [10,36,16,8]
    float* out = (float*)d_out;                // [B,10,16]
    const int B = in_sizes[0] / 9;             // 16384
    dim3 grid(B / M), block(NT);
    capsnet_kernel<<<grid, block, 0, stream>>>(x, cwp, lw, out);
}